// Round 13
// baseline (312.080 us; speedup 1.0000x reference)
//
#include <hip/hip_runtime.h>
#include <hip/hip_bf16.h>
#include <math.h>

#define NB 4
#define HH 128
#define WW 128
#define CC 128
#define GG 8
#define GCC 16
#define KK 9
#define NHW (NB*HH*WW)   // 65536

typedef __hip_bfloat16 bf16;
typedef __attribute__((ext_vector_type(8))) short short8;
typedef __attribute__((ext_vector_type(4))) float f32x4;

__device__ __forceinline__ float b2f(bf16 v){ return __bfloat162float(v); }
__device__ __forceinline__ bf16 f2b(float v){ return __float2bfloat16(v); }
// fast exact-gelu: erf via Abramowitz-Stegun 7.1.26 (|err| <= 1.5e-7), ~15 VALU ops
// vs libm erff's ~40 (branchy). Verified round 1: VALUBusy 48->27%.
__device__ __forceinline__ float gelu_f(float v){
  float x = fabsf(v) * 0.70710678118654752f;
  float t = __builtin_amdgcn_rcpf(fmaf(0.3275911f, x, 1.0f));
  float p = t*fmaf(t, fmaf(t, fmaf(t, fmaf(t, 1.061405429f, -1.453152027f),
                         1.421413741f), -0.284496736f), 0.254829592f);
  float e = __expf(-x*x);
  float er = copysignf(fmaf(-p, e, 1.0f), v);
  return 0.5f*v*(1.0f+er);
}
__device__ __forceinline__ float lo_bf(unsigned u){ union{unsigned i; float f;} c; c.i = u<<16; return c.f; }
__device__ __forceinline__ float hi_bf(unsigned u){ union{unsigned i; float f;} c; c.i = u&0xffff0000u; return c.f; }
__device__ __forceinline__ unsigned pk(float a, float b){
  return ((unsigned)__bfloat16_as_ushort(f2b(b))<<16) | (unsigned)__bfloat16_as_ushort(f2b(a));
}
__device__ __forceinline__ void st_out(bf16* p, float v){ *p = f2b(v); }
__device__ __forceinline__ void st_out(float* p, float v){ *p = v; }
__device__ __forceinline__ void acc8(float* a, uint4 u, float w){
  a[0]+=w*lo_bf(u.x); a[1]+=w*hi_bf(u.x); a[2]+=w*lo_bf(u.y); a[3]+=w*hi_bf(u.y);
  a[4]+=w*lo_bf(u.z); a[5]+=w*hi_bf(u.z); a[6]+=w*lo_bf(u.w); a[7]+=w*hi_bf(u.w);
}

// ---- fused weight prep: 4 transposes + DCN pack, one launch ----
__global__ __launch_bounds__(256) void prep_k(
    const float* __restrict__ inw,  const float* __restrict__ outw,
    const float* __restrict__ fc1w, const float* __restrict__ fc2w,
    const float* __restrict__ offw, const float* __restrict__ offb,
    const float* __restrict__ maskw,const float* __restrict__ maskb,
    bf16* __restrict__ inwt, bf16* __restrict__ outwt,
    bf16* __restrict__ w1t,  bf16* __restrict__ w2t,
    bf16* __restrict__ wsw,  float* __restrict__ cw)
{
  int idx = blockIdx.x*256 + threadIdx.x;
  if (idx < 16384){
    int n = idx>>7, k = idx&127;
    inwt[idx] = f2b(inw[(size_t)k*128 + n]);
  } else if (idx < 32768){
    int i = idx-16384; int n = i>>7, k = i&127;
    outwt[i] = f2b(outw[(size_t)k*128 + n]);
  } else if (idx < 98304){
    int i = idx-32768; int n = i>>7, k = i&127;
    w1t[i] = f2b(fc1w[(size_t)k*512 + n]);
  } else if (idx < 163840){
    int i = idx-98304; int n = i>>9, k = i&511;
    w2t[i] = f2b(fc2w[(size_t)k*128 + n]);
  } else if (idx < 192512){
    int i = idx-163840; int nn = i>>7, k = i&127;
    float v = (nn<144) ? offw[(size_t)k*144+nn] : (nn<216 ? maskw[(size_t)k*72+(nn-144)] : 0.f);
    wsw[i] = f2b(v);
  } else if (idx < 192736){
    int i = idx-192512;
    cw[i] = (i<144) ? offb[i] : (i<216 ? maskb[i-144] : 0.f);
  }
}

// ---------------- LayerNorm over C=128, one wave per pixel ----------------
__global__ __launch_bounds__(256) void ln_k(const float* __restrict__ X,
    const float* __restrict__ gam, const float* __restrict__ bet, bf16* __restrict__ Y)
{
  int lane = threadIdx.x & 63;
  int wid  = threadIdx.x >> 6;
  size_t pix = (size_t)blockIdx.x*4 + wid;
  const float* xp = X + pix*CC;
  int c0 = lane*2;
  float v0 = xp[c0], v1 = xp[c0+1];
  float s = v0+v1, ss = v0*v0+v1*v1;
  #pragma unroll
  for (int off=32; off>0; off>>=1){ s += __shfl_xor(s,off,64); ss += __shfl_xor(ss,off,64); }
  float mean = s*(1.f/CC);
  float var  = ss*(1.f/CC) - mean*mean;
  float rstd = rsqrtf(var + 1e-5f);
  float y0 = (v0-mean)*rstd*gam[c0]   + bet[c0];
  float y1 = (v1-mean)*rstd*gam[c0+1] + bet[c0+1];
  Y[pix*CC + c0]   = f2b(y0);
  Y[pix*CC + c0+1] = f2b(y1);
}

// -------- depthwise 3x3 conv + LN + GELU: 16 px x 16 ch-groups, no LDS --------
__global__ __launch_bounds__(256) void convln_k(const bf16* __restrict__ XN,
    const float* __restrict__ dwk, const float* __restrict__ dwb,
    const float* __restrict__ gam, const float* __restrict__ bet, bf16* __restrict__ X1)
{
  int tid = threadIdx.x;
  int px = tid>>4, cg = tid&15;
  int ch0 = cg*8;
  int pix = blockIdx.x*16 + px;           // 16 px stay within one row (128%16==0)
  int w = pix & (WW-1), h = (pix>>7)&(HH-1), n = pix>>14;
  float acc[8];
  {
    float4 b0 = *(const float4*)(dwb + ch0), b1 = *(const float4*)(dwb + ch0 + 4);
    acc[0]=b0.x; acc[1]=b0.y; acc[2]=b0.z; acc[3]=b0.w;
    acc[4]=b1.x; acc[5]=b1.y; acc[6]=b1.z; acc[7]=b1.w;
  }
  #pragma unroll
  for (int ky=0;ky<3;ky++){
    int yy = h+ky-1; if ((unsigned)yy>=(unsigned)HH) continue;
    #pragma unroll
    for (int kx=0;kx<3;kx++){
      int xx = w+kx-1; if ((unsigned)xx>=(unsigned)WW) continue;
      uint4 u = *(const uint4*)(XN + ((size_t)((n*HH+yy)*WW+xx))*CC + ch0);
      const float* wp = dwk + (ky*3+kx)*CC + ch0;
      float4 w0 = *(const float4*)wp; float4 w1 = *(const float4*)(wp+4);
      acc[0] += lo_bf(u.x)*w0.x; acc[1] += hi_bf(u.x)*w0.y;
      acc[2] += lo_bf(u.y)*w0.z; acc[3] += hi_bf(u.y)*w0.w;
      acc[4] += lo_bf(u.z)*w1.x; acc[5] += hi_bf(u.z)*w1.y;
      acc[6] += lo_bf(u.w)*w1.z; acc[7] += hi_bf(u.w)*w1.w;
    }
  }
  float s=0.f, ss=0.f;
  #pragma unroll
  for (int i=0;i<8;i++){ s += acc[i]; ss += acc[i]*acc[i]; }
  #pragma unroll
  for (int off=1; off<16; off<<=1){ s += __shfl_xor(s,off,64); ss += __shfl_xor(ss,off,64); }
  float mean=s*(1.f/CC), var=ss*(1.f/CC)-mean*mean, rstd=rsqrtf(var+1e-5f);
  float4 g0 = *(const float4*)(gam + ch0), g1 = *(const float4*)(gam + ch0 + 4);
  float4 be0 = *(const float4*)(bet + ch0), be1 = *(const float4*)(bet + ch0 + 4);
  float gv[8] = {g0.x,g0.y,g0.z,g0.w,g1.x,g1.y,g1.z,g1.w};
  float bv[8] = {be0.x,be0.y,be0.z,be0.w,be1.x,be1.y,be1.z,be1.w};
  float o[8];
  #pragma unroll
  for (int i=0;i<8;i++) o[i] = gelu_f((acc[i]-mean)*rstd*gv[i] + bv[i]);
  uint4 up; up.x = pk(o[0],o[1]); up.y = pk(o[2],o[3]); up.z = pk(o[4],o[5]); up.w = pk(o[6],o[7]);
  *(uint4*)(X1 + (size_t)pix*CC + ch0) = up;
}

// ---- fused DCN: MFMA projection + softmax + branchless bilinear sampling ----
#define OMS 226   // oms row stride (bf16): 113 dwords, odd -> banks spread
__global__ __launch_bounds__(256) void samp_k(const bf16* __restrict__ X1,
    const bf16* __restrict__ XP,
    const bf16* __restrict__ wsw, const float* __restrict__ cw,
    bf16* __restrict__ Y)
{
  __shared__ bf16 oms[32*OMS];   // 14464 B
  int tid = threadIdx.x;
  int pix0 = blockIdx.x*32;      // 32 px within one row segment
  int wave = tid>>6, l = tid&63, lo16 = l&15, quad = l>>4;
  // ---- phase 1: scores(32x224) = x1[pix0:pix0+32] @ wsw^T + cw, MFMA ----
  int nt0 = wave*4;
  int ntn = (wave==3) ? 2 : 4;
  short8 af[2][4];
  #pragma unroll
  for (int mt=0;mt<2;mt++)
    #pragma unroll
    for (int ks=0;ks<4;ks++)
      af[mt][ks] = *(const short8*)(X1 + (size_t)(pix0+mt*16+lo16)*128 + ks*32 + quad*8);
  f32x4 z = {0.f,0.f,0.f,0.f};
  f32x4 acc[2][4];
  #pragma unroll
  for (int mt=0;mt<2;mt++)
    #pragma unroll
    for (int t=0;t<4;t++) acc[mt][t]=z;
  for (int t=0;t<ntn;t++){
    int nt = nt0+t;
    #pragma unroll
    for (int ks=0;ks<4;ks++){
      short8 bfr = *(const short8*)(wsw + (size_t)(nt*16+lo16)*128 + ks*32 + quad*8);
      acc[0][t] = __builtin_amdgcn_mfma_f32_16x16x32_bf16(af[0][ks], bfr, acc[0][t], 0,0,0);
      acc[1][t] = __builtin_amdgcn_mfma_f32_16x16x32_bf16(af[1][ks], bfr, acc[1][t], 0,0,0);
    }
  }
  for (int t=0;t<ntn;t++){
    int col = (nt0+t)*16 + lo16;
    float bb = cw[col];
    #pragma unroll
    for (int mt=0;mt<2;mt++)
      #pragma unroll
      for (int r=0;r<4;r++)
        oms[(mt*16 + quad*4 + r)*OMS + col] = f2b(acc[mt][t][r] + bb);
  }
  __syncthreads();
  // ---- phase 2: softmax, task = (px, group), 32*8 = 256 ----
  {
    int m = tid>>3, g = tid&7;
    int base = m*OMS + 144 + g*9;
    float sc[9]; float mx = -1e30f;
    #pragma unroll
    for (int k=0;k<9;k++){ sc[k] = b2f(oms[base+k]); mx = fmaxf(mx, sc[k]); }
    float sum = 0.f;
    #pragma unroll
    for (int k=0;k<9;k++){ sc[k] = expf(sc[k]-mx); sum += sc[k]; }
    float inv = 1.f/sum;
    #pragma unroll
    for (int k=0;k<9;k++) oms[base+k] = f2b(sc[k]*inv);
  }
  __syncthreads();
  // ---- phase 3: branchless sampling; lane = ch-oct, slot = tid>>4 ----
  int oct = tid&15, sl = tid>>4;
  int g = oct>>1;
  int ch = g*GCC + (oct&1)*8;
  int w0 = pix0 & (WW-1);
  int h  = (pix0>>7) & (HH-1);
  int n  = pix0>>14;
  const bf16* base = XP + (size_t)n*HH*WW*CC + ch;
  for (int it=0; it<2; it++){
    int m = it*16 + sl;
    int wc = w0 + m;
    const bf16* omrow = &oms[m*OMS];
    float a[8] = {0.f,0.f,0.f,0.f,0.f,0.f,0.f,0.f};
    #pragma unroll
    for (int k=0;k<9;k++){
      float offx = b2f(omrow[g*18 + 2*k]);
      float offy = b2f(omrow[g*18 + 2*k + 1]);
      float mk   = b2f(omrow[144 + g*9 + k]);
      float pxf = (float)(wc + (k/3) - 1) + offx;   // x-major grid
      float pyf = (float)(h  + (k%3) - 1) + offy;
      float x0f = floorf(pxf), y0f = floorf(pyf);
      float txf = pxf-x0f,     tyf = pyf-y0f;
      int x0 = (int)x0f, y0 = (int)y0f;
      int x1i = x0+1,    y1i = y0+1;
      float vx0 = ((unsigned)x0 <(unsigned)WW)?1.f:0.f;
      float vx1 = ((unsigned)x1i<(unsigned)WW)?1.f:0.f;
      float vy0 = ((unsigned)y0 <(unsigned)HH)?1.f:0.f;
      float vy1 = ((unsigned)y1i<(unsigned)HH)?1.f:0.f;
      int cx0 = min(max(x0,0),WW-1),  cx1 = min(max(x1i,0),WW-1);
      int cy0 = min(max(y0,0),HH-1),  cy1 = min(max(y1i,0),HH-1);
      float w00=(1.f-tyf)*(1.f-txf)*mk*vy0*vx0, w01=(1.f-tyf)*txf*mk*vy0*vx1;
      float w10=tyf*(1.f-txf)*mk*vy1*vx0,       w11=tyf*txf*mk*vy1*vx1;
      uint4 u00 = *(const uint4*)(base + ((size_t)(cy0*WW+cx0))*CC);
      uint4 u01 = *(const uint4*)(base + ((size_t)(cy0*WW+cx1))*CC);
      uint4 u10 = *(const uint4*)(base + ((size_t)(cy1*WW+cx0))*CC);
      uint4 u11 = *(const uint4*)(base + ((size_t)(cy1*WW+cx1))*CC);
      acc8(a,u00,w00); acc8(a,u01,w01); acc8(a,u10,w10); acc8(a,u11,w11);
    }
    uint4 outp;
    outp.x = pk(a[0],a[1]); outp.y = pk(a[2],a[3]);
    outp.z = pk(a[4],a[5]); outp.w = pk(a[6],a[7]);
    *(uint4*)(Y + (size_t)(pix0+m)*CC + ch) = outp;
  }
}

// ------------- MFMA GEMM: C(Mx128) = A(Mx128 bf16) @ Bt^T + bias (+res) -------------
// 4 m-tiles/wave, grid (2,256): measured-good config.
template<typename OutT, bool RES>
__global__ __launch_bounds__(256) void gemm_mfma(const bf16* __restrict__ A,
    const bf16* __restrict__ Bt, const float* __restrict__ bias,
    const float* __restrict__ res, OutT* __restrict__ C)
{
  int tid = threadIdx.x;
  int wave = tid>>6, l = tid&63, lo16 = l&15, quad = l>>4;
  int m0 = blockIdx.y*256 + wave*64;
  int n0 = blockIdx.x*64;
  short8 bfr[4][4];   // [kstep][ntile]
  #pragma unroll
  for (int ks=0;ks<4;ks++)
    #pragma unroll
    for (int nt=0;nt<4;nt++)
      bfr[ks][nt] = *(const short8*)(Bt + (size_t)(n0+nt*16+lo16)*128 + ks*32 + quad*8);
  f32x4 z = {0.f,0.f,0.f,0.f};
  f32x4 acc[4][4];
  #pragma unroll
  for (int mt=0;mt<4;mt++)
    #pragma unroll
    for (int nt=0;nt<4;nt++) acc[mt][nt]=z;
  #pragma unroll
  for (int ks=0;ks<4;ks++){
    short8 af[4];
    #pragma unroll
    for (int mt=0;mt<4;mt++)
      af[mt] = *(const short8*)(A + (size_t)(m0+mt*16+lo16)*128 + ks*32 + quad*8);
    #pragma unroll
    for (int nt=0;nt<4;nt++)
      #pragma unroll
      for (int mt=0;mt<4;mt++)
        acc[mt][nt] = __builtin_amdgcn_mfma_f32_16x16x32_bf16(af[mt], bfr[ks][nt], acc[mt][nt], 0,0,0);
  }
  #pragma unroll
  for (int mt=0;mt<4;mt++)
    #pragma unroll
    for (int nt=0;nt<4;nt++){
      int col = n0 + nt*16 + lo16;
      float bb = bias[col];
      #pragma unroll
      for (int r=0;r<4;r++){
        int row = m0 + mt*16 + quad*4 + r;
        float v = acc[mt][nt][r] + bb;
        if (RES) v += res[(size_t)row*128 + col];
        st_out(&C[(size_t)row*128 + col], v);
      }
    }
}

// ---- fused MFMA MLP: r7 dataflow + T14 issue-early/write-late staging ----
// r7 = 4 barriers/iter with stage latency exposed between barriers (65.7us).
// This round: per iteration {issue 8 global loads for chunk c+1 into regs ->
// fc1 -> gelu->ts -> fc2 -> barrier A -> ds_write regs -> barrier B}.
// 2 barriers/iter; load latency hides under ~1000+cy of compute; the vmcnt
// wait lands at the ds_write after compute (T14, Guideline 15).
// Race audit: w1s/w2s reads live strictly (B, next A); writes strictly (A, B).
// ts is wave-private same-wave write->read (lgkm-ordered, r4-verified).
// a1 reads fenced from prologue stage (h0s alias) by a dedicated barrier.
// Loads use cn=(c+1)&7 -> unconditional (no conditional liveness, r1 lesson);
// c=7 stages chunk 0 redundantly (dead but harmless).
// LDS 53248: ts 128x68 [0,17408) | w1s 64x136 [17408,34816) | w2s 128x72
// [34816,53248); h0s 128x136 aliases [0,34816), prologue-only.
__global__ __launch_bounds__(256) void mlp_mfma(const float* __restrict__ X2,
    const float* __restrict__ lng, const float* __restrict__ lnb,
    const bf16* __restrict__ w1t, const float* __restrict__ b1,
    const bf16* __restrict__ w2t, const float* __restrict__ b2,
    float* __restrict__ OUT)
{
  __shared__ __align__(16) char smem[53248];
  bf16* h0s = (bf16*)smem;             // 128 x 136 (prologue only)
  bf16* ts  = (bf16*)smem;             // 128 x 68
  bf16* w1s = (bf16*)(smem + 17408);   // 64 x 136
  bf16* w2s = (bf16*)(smem + 34816);   // 128 x 72
  int tid = threadIdx.x;
  int wave = tid>>6, l = tid&63, lo16 = l&15, quad = l>>4;
  int m0 = blockIdx.x*128;
  int t8 = tid*8;
  // ---- LN2 prologue -> h0s (r7 verbatim) ----
  #pragma unroll
  for (int itn=0; itn<2; itn++){
    int px = (tid>>2) + itn*64;
    int q = tid&3;
    const float* xr = X2 + (size_t)(m0+px)*128 + q*32;
    float v[32];
    #pragma unroll
    for (int i=0;i<8;i++) *(float4*)(v+i*4) = *(const float4*)(xr+i*4);
    float s=0.f, ss=0.f;
    #pragma unroll
    for (int i=0;i<32;i++){ s += v[i]; ss += v[i]*v[i]; }
    s  += __shfl_xor(s,1,64);  ss += __shfl_xor(ss,1,64);
    s  += __shfl_xor(s,2,64);  ss += __shfl_xor(ss,2,64);
    float mean = s*(1.f/CC), var = ss*(1.f/CC)-mean*mean, rstd = rsqrtf(var+1e-5f);
    const float* gp = lng + q*32; const float* bp = lnb + q*32;
    uint4* dst = (uint4*)(&h0s[px*136 + q*32]);
    #pragma unroll
    for (int i=0;i<4;i++){
      float4 g0 = *(const float4*)(gp+i*8),  g1 = *(const float4*)(gp+i*8+4);
      float4 c0v = *(const float4*)(bp+i*8), c1v = *(const float4*)(bp+i*8+4);
      float o0 = (v[i*8+0]-mean)*rstd*g0.x + c0v.x;
      float o1 = (v[i*8+1]-mean)*rstd*g0.y + c0v.y;
      float o2 = (v[i*8+2]-mean)*rstd*g0.z + c0v.z;
      float o3 = (v[i*8+3]-mean)*rstd*g0.w + c0v.w;
      float o4 = (v[i*8+4]-mean)*rstd*g1.x + c1v.x;
      float o5 = (v[i*8+5]-mean)*rstd*g1.y + c1v.y;
      float o6 = (v[i*8+6]-mean)*rstd*g1.z + c1v.z;
      float o7 = (v[i*8+7]-mean)*rstd*g1.w + c1v.w;
      uint4 up; up.x = pk(o0,o1); up.y = pk(o2,o3); up.z = pk(o4,o5); up.w = pk(o6,o7);
      dst[i] = up;
    }
  }
  __syncthreads();
  short8 a1[2][4];
  #pragma unroll
  for (int mt=0;mt<2;mt++)
    #pragma unroll
    for (int ks=0;ks<4;ks++)
      a1[mt][ks] = *(const short8*)(&h0s[(wave*32 + mt*16 + lo16)*136 + ks*32 + quad*8]);
  __syncthreads();                     // a1 reads done before stage clobbers h0s alias
  // ---- prologue: stage chunk 0 directly ----
  #pragma unroll
  for (int it=0;it<4;it++){
    int e = it*2048 + t8;
    *(uint4*)(&w1s[(e>>7)*136 + (e&127)]) = *(const uint4*)(w1t + (size_t)(e>>7)*128 + (e&127));
    *(uint4*)(&w2s[(e>>6)*72 + (e&63)])   = *(const uint4*)(w2t + (size_t)(e>>6)*512 + (e&63));
  }
  __syncthreads();                     // chunk 0 visible

  f32x4 z = {0.f,0.f,0.f,0.f};
  f32x4 acc2[2][8];
  #pragma unroll
  for (int mt=0;mt<2;mt++)
    #pragma unroll
    for (int nt=0;nt<8;nt++) acc2[mt][nt]=z;

  for (int c=0;c<8;c++){
    int c0 = c*64;
    int cn = ((c+1)&7)*64;
    // ---- issue next-chunk loads early (latency hides under compute) ----
    uint4 pw1[4], pw2[4];
    #pragma unroll
    for (int it=0;it<4;it++){
      int e = it*2048 + t8;
      pw1[it] = *(const uint4*)(w1t + (size_t)(cn + (e>>7))*128 + (e&127));
      pw2[it] = *(const uint4*)(w2t + (size_t)(e>>6)*512 + cn + (e&63));
    }
    // ---- fc1 from w1s (chunk c) ----
    f32x4 acc1[2][4];
    #pragma unroll
    for (int mt=0;mt<2;mt++)
      #pragma unroll
      for (int nt=0;nt<4;nt++) acc1[mt][nt]=z;
    #pragma unroll
    for (int ks=0;ks<4;ks++)
      #pragma unroll
      for (int nt=0;nt<4;nt++){
        short8 bfr = *(const short8*)(&w1s[(nt*16+lo16)*136 + ks*32 + quad*8]);
        acc1[0][nt] = __builtin_amdgcn_mfma_f32_16x16x32_bf16(a1[0][ks], bfr, acc1[0][nt], 0,0,0);
        acc1[1][nt] = __builtin_amdgcn_mfma_f32_16x16x32_bf16(a1[1][ks], bfr, acc1[1][nt], 0,0,0);
      }
    // ---- gelu -> ts (wave-private rows, same-wave write->read) ----
    #pragma unroll
    for (int mt=0;mt<2;mt++)
      #pragma unroll
      for (int nt=0;nt<4;nt++){
        float bb = b1[c0 + nt*16 + lo16];
        #pragma unroll
        for (int r=0;r<4;r++)
          ts[(wave*32 + mt*16 + quad*4 + r)*68 + nt*16 + lo16] = f2b(gelu_f(acc1[mt][nt][r] + bb));
      }
    // ---- fc2 from ts + w2s (chunk c) ----
    #pragma unroll
    for (int ks2=0;ks2<2;ks2++){
      short8 a2[2];
      #pragma unroll
      for (int mt=0;mt<2;mt++)
        a2[mt] = *(const short8*)(&ts[(wave*32 + mt*16 + lo16)*68 + ks2*32 + quad*8]);
      #pragma unroll
      for (int nt2=0;nt2<8;nt2++){
        short8 bfr2 = *(const short8*)(&w2s[(nt2*16+lo16)*72 + ks2*32 + quad*8]);
        acc2[0][nt2] = __builtin_amdgcn_mfma_f32_16x16x32_bf16(a2[0], bfr2, acc2[0][nt2], 0,0,0);
        acc2[1][nt2] = __builtin_amdgcn_mfma_f32_16x16x32_bf16(a2[1], bfr2, acc2[1][nt2], 0,0,0);
      }
    }
    __syncthreads();                   // (A) all reads of chunk c done
    #pragma unroll
    for (int it=0;it<4;it++){
      int e = it*2048 + t8;
      *(uint4*)(&w1s[(e>>7)*136 + (e&127)]) = pw1[it];
      *(uint4*)(&w2s[(e>>6)*72 + (e&63)])   = pw2[it];
    }
    __syncthreads();                   // (B) chunk c+1 visible
  }
  #pragma unroll
  for (int mt=0;mt<2;mt++)
    #pragma unroll
    for (int nt=0;nt<8;nt++){
      int col = nt*16 + lo16;
      float bb = b2[col];
      #pragma unroll
      for (int r=0;r<4;r++){
        int row = m0 + wave*32 + mt*16 + quad*4 + r;
        float v = acc2[mt][nt][r] + bb + X2[(size_t)row*128 + col];
        OUT[(size_t)row*128 + col] = v;
      }
    }
}

extern "C" void kernel_launch(void* const* d_in, const int* in_sizes, int n_in,
                              void* d_out, int out_size, void* d_ws, size_t ws_size,
                              hipStream_t stream)
{
  const float* x    = (const float*)d_in[0];
  const float* ln1g = (const float*)d_in[1];
  const float* ln1b = (const float*)d_in[2];
  const float* inw  = (const float*)d_in[3];
  const float* inb  = (const float*)d_in[4];
  const float* dwk  = (const float*)d_in[5];
  const float* dwb  = (const float*)d_in[6];
  const float* dwlng= (const float*)d_in[7];
  const float* dwlnb= (const float*)d_in[8];
  const float* offw = (const float*)d_in[9];
  const float* offb = (const float*)d_in[10];
  const float* maskw= (const float*)d_in[11];
  const float* maskb= (const float*)d_in[12];
  const float* outw = (const float*)d_in[13];
  const float* outb = (const float*)d_in[14];
  const float* ln2g = (const float*)d_in[15];
  const float* ln2b = (const float*)d_in[16];
  const float* fc1w = (const float*)d_in[17];
  const float* fc1b = (const float*)d_in[18];
  const float* fc2w = (const float*)d_in[19];
  const float* fc2b = (const float*)d_in[20];
  float* out = (float*)d_out;

  bf16* ws = (bf16*)d_ws;
  const size_t S = (size_t)NHW*CC;
  bf16* xn = ws;
  bf16* xp = ws + S;
  bf16* x1 = ws + 2*S;
  bf16* y  = xn;
  float* x2 = out;
  bf16* inwt  = ws + 3*S;
  bf16* outwt = inwt + 128*128;
  bf16* w1t   = outwt + 128*128;
  bf16* w2t   = w1t + 512*128;
  bf16* wsw   = w2t + 128*512;
  float* cw   = (float*)(wsw + 224*128);

  prep_k<<<753, 256, 0, stream>>>(inw, outw, fc1w, fc2w, offw, offb, maskw, maskb,
                                  inwt, outwt, w1t, w2t, wsw, cw);
  ln_k<<<NHW/4, 256, 0, stream>>>(x, ln1g, ln1b, xn);
  gemm_mfma<bf16,false><<<dim3(2,256), 256, 0, stream>>>(xn, inwt, inb, nullptr, xp);
  convln_k<<<NHW/16, 256, 0, stream>>>(xn, dwk, dwb, dwlng, dwlnb, x1);
  samp_k<<<NHW/32, 256, 0, stream>>>(x1, xp, wsw, cw, y);
  gemm_mfma<float,true><<<dim3(2,256), 256, 0, stream>>>(y, outwt, outb, x, x2);
  mlp_mfma<<<NHW/128, 256, 0, stream>>>(x2, ln2g, ln2b, w1t, fc1b, w2t, fc2b, out);
}

// Round 14
// 281.007 us; speedup vs baseline: 1.1106x; 1.1106x over previous
//
#include <hip/hip_runtime.h>
#include <hip/hip_bf16.h>
#include <math.h>

#define NB 4
#define HH 128
#define WW 128
#define CC 128
#define GG 8
#define GCC 16
#define KK 9
#define NHW (NB*HH*WW)   // 65536

typedef __hip_bfloat16 bf16;
typedef __attribute__((ext_vector_type(8))) short short8;
typedef __attribute__((ext_vector_type(4))) float f32x4;

__device__ __forceinline__ float b2f(bf16 v){ return __bfloat162float(v); }
__device__ __forceinline__ bf16 f2b(float v){ return __float2bfloat16(v); }
// fast exact-gelu: erf via Abramowitz-Stegun 7.1.26 (|err| <= 1.5e-7), ~15 VALU ops
// vs libm erff's ~40 (branchy). Verified round 1: VALUBusy 48->27%.
__device__ __forceinline__ float gelu_f(float v){
  float x = fabsf(v) * 0.70710678118654752f;
  float t = __builtin_amdgcn_rcpf(fmaf(0.3275911f, x, 1.0f));
  float p = t*fmaf(t, fmaf(t, fmaf(t, fmaf(t, 1.061405429f, -1.453152027f),
                         1.421413741f), -0.284496736f), 0.254829592f);
  float e = __expf(-x*x);
  float er = copysignf(fmaf(-p, e, 1.0f), v);
  return 0.5f*v*(1.0f+er);
}
__device__ __forceinline__ float lo_bf(unsigned u){ union{unsigned i; float f;} c; c.i = u<<16; return c.f; }
__device__ __forceinline__ float hi_bf(unsigned u){ union{unsigned i; float f;} c; c.i = u&0xffff0000u; return c.f; }
__device__ __forceinline__ unsigned pk(float a, float b){
  return ((unsigned)__bfloat16_as_ushort(f2b(b))<<16) | (unsigned)__bfloat16_as_ushort(f2b(a));
}
__device__ __forceinline__ void st_out(bf16* p, float v){ *p = f2b(v); }
__device__ __forceinline__ void st_out(float* p, float v){ *p = v; }
__device__ __forceinline__ void acc8(float* a, uint4 u, float w){
  a[0]+=w*lo_bf(u.x); a[1]+=w*hi_bf(u.x); a[2]+=w*lo_bf(u.y); a[3]+=w*hi_bf(u.y);
  a[4]+=w*lo_bf(u.z); a[5]+=w*hi_bf(u.z); a[6]+=w*lo_bf(u.w); a[7]+=w*hi_bf(u.w);
}

// ---- fused weight prep: 4 transposes + DCN pack, one launch ----
__global__ __launch_bounds__(256) void prep_k(
    const float* __restrict__ inw,  const float* __restrict__ outw,
    const float* __restrict__ fc1w, const float* __restrict__ fc2w,
    const float* __restrict__ offw, const float* __restrict__ offb,
    const float* __restrict__ maskw,const float* __restrict__ maskb,
    bf16* __restrict__ inwt, bf16* __restrict__ outwt,
    bf16* __restrict__ w1t,  bf16* __restrict__ w2t,
    bf16* __restrict__ wsw,  float* __restrict__ cw)
{
  int idx = blockIdx.x*256 + threadIdx.x;
  if (idx < 16384){
    int n = idx>>7, k = idx&127;
    inwt[idx] = f2b(inw[(size_t)k*128 + n]);
  } else if (idx < 32768){
    int i = idx-16384; int n = i>>7, k = i&127;
    outwt[i] = f2b(outw[(size_t)k*128 + n]);
  } else if (idx < 98304){
    int i = idx-32768; int n = i>>7, k = i&127;
    w1t[i] = f2b(fc1w[(size_t)k*512 + n]);
  } else if (idx < 163840){
    int i = idx-98304; int n = i>>9, k = i&511;
    w2t[i] = f2b(fc2w[(size_t)k*128 + n]);
  } else if (idx < 192512){
    int i = idx-163840; int nn = i>>7, k = i&127;
    float v = (nn<144) ? offw[(size_t)k*144+nn] : (nn<216 ? maskw[(size_t)k*72+(nn-144)] : 0.f);
    wsw[i] = f2b(v);
  } else if (idx < 192736){
    int i = idx-192512;
    cw[i] = (i<144) ? offb[i] : (i<216 ? maskb[i-144] : 0.f);
  }
}

// ---------------- LayerNorm over C=128, one wave per pixel ----------------
__global__ __launch_bounds__(256) void ln_k(const float* __restrict__ X,
    const float* __restrict__ gam, const float* __restrict__ bet, bf16* __restrict__ Y)
{
  int lane = threadIdx.x & 63;
  int wid  = threadIdx.x >> 6;
  size_t pix = (size_t)blockIdx.x*4 + wid;
  const float* xp = X + pix*CC;
  int c0 = lane*2;
  float v0 = xp[c0], v1 = xp[c0+1];
  float s = v0+v1, ss = v0*v0+v1*v1;
  #pragma unroll
  for (int off=32; off>0; off>>=1){ s += __shfl_xor(s,off,64); ss += __shfl_xor(ss,off,64); }
  float mean = s*(1.f/CC);
  float var  = ss*(1.f/CC) - mean*mean;
  float rstd = rsqrtf(var + 1e-5f);
  float y0 = (v0-mean)*rstd*gam[c0]   + bet[c0];
  float y1 = (v1-mean)*rstd*gam[c0+1] + bet[c0+1];
  Y[pix*CC + c0]   = f2b(y0);
  Y[pix*CC + c0+1] = f2b(y1);
}

// -------- depthwise 3x3 conv + LN + GELU: 16 px x 16 ch-groups, no LDS --------
__global__ __launch_bounds__(256) void convln_k(const bf16* __restrict__ XN,
    const float* __restrict__ dwk, const float* __restrict__ dwb,
    const float* __restrict__ gam, const float* __restrict__ bet, bf16* __restrict__ X1)
{
  int tid = threadIdx.x;
  int px = tid>>4, cg = tid&15;
  int ch0 = cg*8;
  int pix = blockIdx.x*16 + px;           // 16 px stay within one row (128%16==0)
  int w = pix & (WW-1), h = (pix>>7)&(HH-1), n = pix>>14;
  float acc[8];
  {
    float4 b0 = *(const float4*)(dwb + ch0), b1 = *(const float4*)(dwb + ch0 + 4);
    acc[0]=b0.x; acc[1]=b0.y; acc[2]=b0.z; acc[3]=b0.w;
    acc[4]=b1.x; acc[5]=b1.y; acc[6]=b1.z; acc[7]=b1.w;
  }
  #pragma unroll
  for (int ky=0;ky<3;ky++){
    int yy = h+ky-1; if ((unsigned)yy>=(unsigned)HH) continue;
    #pragma unroll
    for (int kx=0;kx<3;kx++){
      int xx = w+kx-1; if ((unsigned)xx>=(unsigned)WW) continue;
      uint4 u = *(const uint4*)(XN + ((size_t)((n*HH+yy)*WW+xx))*CC + ch0);
      const float* wp = dwk + (ky*3+kx)*CC + ch0;
      float4 w0 = *(const float4*)wp; float4 w1 = *(const float4*)(wp+4);
      acc[0] += lo_bf(u.x)*w0.x; acc[1] += hi_bf(u.x)*w0.y;
      acc[2] += lo_bf(u.y)*w0.z; acc[3] += hi_bf(u.y)*w0.w;
      acc[4] += lo_bf(u.z)*w1.x; acc[5] += hi_bf(u.z)*w1.y;
      acc[6] += lo_bf(u.w)*w1.z; acc[7] += hi_bf(u.w)*w1.w;
    }
  }
  float s=0.f, ss=0.f;
  #pragma unroll
  for (int i=0;i<8;i++){ s += acc[i]; ss += acc[i]*acc[i]; }
  #pragma unroll
  for (int off=1; off<16; off<<=1){ s += __shfl_xor(s,off,64); ss += __shfl_xor(ss,off,64); }
  float mean=s*(1.f/CC), var=ss*(1.f/CC)-mean*mean, rstd=rsqrtf(var+1e-5f);
  float4 g0 = *(const float4*)(gam + ch0), g1 = *(const float4*)(gam + ch0 + 4);
  float4 be0 = *(const float4*)(bet + ch0), be1 = *(const float4*)(bet + ch0 + 4);
  float gv[8] = {g0.x,g0.y,g0.z,g0.w,g1.x,g1.y,g1.z,g1.w};
  float bv[8] = {be0.x,be0.y,be0.z,be0.w,be1.x,be1.y,be1.z,be1.w};
  float o[8];
  #pragma unroll
  for (int i=0;i<8;i++) o[i] = gelu_f((acc[i]-mean)*rstd*gv[i] + bv[i]);
  uint4 up; up.x = pk(o[0],o[1]); up.y = pk(o[2],o[3]); up.z = pk(o[4],o[5]); up.w = pk(o[6],o[7]);
  *(uint4*)(X1 + (size_t)pix*CC + ch0) = up;
}

// ---- fused DCN: MFMA projection + softmax + branchless bilinear sampling ----
#define OMS 226   // oms row stride (bf16): 113 dwords, odd -> banks spread
__global__ __launch_bounds__(256) void samp_k(const bf16* __restrict__ X1,
    const bf16* __restrict__ XP,
    const bf16* __restrict__ wsw, const float* __restrict__ cw,
    bf16* __restrict__ Y)
{
  __shared__ bf16 oms[32*OMS];   // 14464 B
  int tid = threadIdx.x;
  int pix0 = blockIdx.x*32;      // 32 px within one row segment
  int wave = tid>>6, l = tid&63, lo16 = l&15, quad = l>>4;
  // ---- phase 1: scores(32x224) = x1[pix0:pix0+32] @ wsw^T + cw, MFMA ----
  int nt0 = wave*4;
  int ntn = (wave==3) ? 2 : 4;
  short8 af[2][4];
  #pragma unroll
  for (int mt=0;mt<2;mt++)
    #pragma unroll
    for (int ks=0;ks<4;ks++)
      af[mt][ks] = *(const short8*)(X1 + (size_t)(pix0+mt*16+lo16)*128 + ks*32 + quad*8);
  f32x4 z = {0.f,0.f,0.f,0.f};
  f32x4 acc[2][4];
  #pragma unroll
  for (int mt=0;mt<2;mt++)
    #pragma unroll
    for (int t=0;t<4;t++) acc[mt][t]=z;
  for (int t=0;t<ntn;t++){
    int nt = nt0+t;
    #pragma unroll
    for (int ks=0;ks<4;ks++){
      short8 bfr = *(const short8*)(wsw + (size_t)(nt*16+lo16)*128 + ks*32 + quad*8);
      acc[0][t] = __builtin_amdgcn_mfma_f32_16x16x32_bf16(af[0][ks], bfr, acc[0][t], 0,0,0);
      acc[1][t] = __builtin_amdgcn_mfma_f32_16x16x32_bf16(af[1][ks], bfr, acc[1][t], 0,0,0);
    }
  }
  for (int t=0;t<ntn;t++){
    int col = (nt0+t)*16 + lo16;
    float bb = cw[col];
    #pragma unroll
    for (int mt=0;mt<2;mt++)
      #pragma unroll
      for (int r=0;r<4;r++)
        oms[(mt*16 + quad*4 + r)*OMS + col] = f2b(acc[mt][t][r] + bb);
  }
  __syncthreads();
  // ---- phase 2: softmax, task = (px, group), 32*8 = 256 ----
  {
    int m = tid>>3, g = tid&7;
    int base = m*OMS + 144 + g*9;
    float sc[9]; float mx = -1e30f;
    #pragma unroll
    for (int k=0;k<9;k++){ sc[k] = b2f(oms[base+k]); mx = fmaxf(mx, sc[k]); }
    float sum = 0.f;
    #pragma unroll
    for (int k=0;k<9;k++){ sc[k] = expf(sc[k]-mx); sum += sc[k]; }
    float inv = 1.f/sum;
    #pragma unroll
    for (int k=0;k<9;k++) oms[base+k] = f2b(sc[k]*inv);
  }
  __syncthreads();
  // ---- phase 3: branchless sampling; lane = ch-oct, slot = tid>>4 ----
  int oct = tid&15, sl = tid>>4;
  int g = oct>>1;
  int ch = g*GCC + (oct&1)*8;
  int w0 = pix0 & (WW-1);
  int h  = (pix0>>7) & (HH-1);
  int n  = pix0>>14;
  const bf16* base = XP + (size_t)n*HH*WW*CC + ch;
  for (int it=0; it<2; it++){
    int m = it*16 + sl;
    int wc = w0 + m;
    const bf16* omrow = &oms[m*OMS];
    float a[8] = {0.f,0.f,0.f,0.f,0.f,0.f,0.f,0.f};
    #pragma unroll
    for (int k=0;k<9;k++){
      float offx = b2f(omrow[g*18 + 2*k]);
      float offy = b2f(omrow[g*18 + 2*k + 1]);
      float mk   = b2f(omrow[144 + g*9 + k]);
      float pxf = (float)(wc + (k/3) - 1) + offx;   // x-major grid
      float pyf = (float)(h  + (k%3) - 1) + offy;
      float x0f = floorf(pxf), y0f = floorf(pyf);
      float txf = pxf-x0f,     tyf = pyf-y0f;
      int x0 = (int)x0f, y0 = (int)y0f;
      int x1i = x0+1,    y1i = y0+1;
      float vx0 = ((unsigned)x0 <(unsigned)WW)?1.f:0.f;
      float vx1 = ((unsigned)x1i<(unsigned)WW)?1.f:0.f;
      float vy0 = ((unsigned)y0 <(unsigned)HH)?1.f:0.f;
      float vy1 = ((unsigned)y1i<(unsigned)HH)?1.f:0.f;
      int cx0 = min(max(x0,0),WW-1),  cx1 = min(max(x1i,0),WW-1);
      int cy0 = min(max(y0,0),HH-1),  cy1 = min(max(y1i,0),HH-1);
      float w00=(1.f-tyf)*(1.f-txf)*mk*vy0*vx0, w01=(1.f-tyf)*txf*mk*vy0*vx1;
      float w10=tyf*(1.f-txf)*mk*vy1*vx0,       w11=tyf*txf*mk*vy1*vx1;
      uint4 u00 = *(const uint4*)(base + ((size_t)(cy0*WW+cx0))*CC);
      uint4 u01 = *(const uint4*)(base + ((size_t)(cy0*WW+cx1))*CC);
      uint4 u10 = *(const uint4*)(base + ((size_t)(cy1*WW+cx0))*CC);
      uint4 u11 = *(const uint4*)(base + ((size_t)(cy1*WW+cx1))*CC);
      acc8(a,u00,w00); acc8(a,u01,w01); acc8(a,u10,w10); acc8(a,u11,w11);
    }
    uint4 outp;
    outp.x = pk(a[0],a[1]); outp.y = pk(a[2],a[3]);
    outp.z = pk(a[4],a[5]); outp.w = pk(a[6],a[7]);
    *(uint4*)(Y + (size_t)(pix0+m)*CC + ch) = outp;
  }
}

// ------------- MFMA GEMM: C(Mx128) = A(Mx128 bf16) @ Bt^T + bias (+res) -------------
// 4 m-tiles/wave, grid (2,256): measured-good config (r6's 1-mtile split cost ~10us).
template<typename OutT, bool RES>
__global__ __launch_bounds__(256) void gemm_mfma(const bf16* __restrict__ A,
    const bf16* __restrict__ Bt, const float* __restrict__ bias,
    const float* __restrict__ res, OutT* __restrict__ C)
{
  int tid = threadIdx.x;
  int wave = tid>>6, l = tid&63, lo16 = l&15, quad = l>>4;
  int m0 = blockIdx.y*256 + wave*64;
  int n0 = blockIdx.x*64;
  short8 bfr[4][4];   // [kstep][ntile]
  #pragma unroll
  for (int ks=0;ks<4;ks++)
    #pragma unroll
    for (int nt=0;nt<4;nt++)
      bfr[ks][nt] = *(const short8*)(Bt + (size_t)(n0+nt*16+lo16)*128 + ks*32 + quad*8);
  f32x4 z = {0.f,0.f,0.f,0.f};
  f32x4 acc[4][4];
  #pragma unroll
  for (int mt=0;mt<4;mt++)
    #pragma unroll
    for (int nt=0;nt<4;nt++) acc[mt][nt]=z;
  #pragma unroll
  for (int ks=0;ks<4;ks++){
    short8 af[4];
    #pragma unroll
    for (int mt=0;mt<4;mt++)
      af[mt] = *(const short8*)(A + (size_t)(m0+mt*16+lo16)*128 + ks*32 + quad*8);
    #pragma unroll
    for (int nt=0;nt<4;nt++)
      #pragma unroll
      for (int mt=0;mt<4;mt++)
        acc[mt][nt] = __builtin_amdgcn_mfma_f32_16x16x32_bf16(af[mt], bfr[ks][nt], acc[mt][nt], 0,0,0);
  }
  #pragma unroll
  for (int mt=0;mt<4;mt++)
    #pragma unroll
    for (int nt=0;nt<4;nt++){
      int col = n0 + nt*16 + lo16;
      float bb = bias[col];
      #pragma unroll
      for (int r=0;r<4;r++){
        int row = m0 + mt*16 + quad*4 + r;
        float v = acc[mt][nt][r] + bb;
        if (RES) v += res[(size_t)row*128 + col];
        st_out(&C[(size_t)row*128 + col], v);
      }
    }
}

// ---- fused MFMA MLP with internal LN2, LDS-staged weights, 128 px/block ----
// SESSION-BEST CONFIG (r7: 282.4us total, r12 re-verify: 285.0us): r0
// structure (h0s prologue, 4-barrier alternating stage) + fast gelu.
// All structural alternatives measured worse: merged stage (69.5), in-reg-LN
// 4-barrier (71.4), 128-thread 4-domain (80), T14 reg-prefetch (92 -- hipcc
// spills cross-barrier load aggregates to scratch, confirmed r1+r13),
// barrier-free (98, load-chain-bound regardless of coalescing), gemm2-fusion
// (113, VGPR 152 + occupancy collapse). The ~40us over the VALU+MFMA floor is
// the vmcnt(0)-drain-before-barrier ceiling; escaping it needs an inline-asm
// counted-vmcnt pipeline (s_barrier + vmcnt(N)), not attempted headlessly.
// LDS: h0s 128x136 [0,34816) | ts 128x72 aliases h0s | w1s/w2s alternate at +34816.
__global__ __launch_bounds__(256) void mlp_mfma(const float* __restrict__ X2,
    const float* __restrict__ lng, const float* __restrict__ lnb,
    const bf16* __restrict__ w1t, const float* __restrict__ b1,
    const bf16* __restrict__ w2t, const float* __restrict__ b2,
    float* __restrict__ OUT)
{
  __shared__ __align__(16) char smem[34816 + 18432];
  bf16* h0s = (bf16*)smem;             // 128 x 136
  bf16* ts  = (bf16*)smem;             // 128 x 72 (aliases h0s after a1 loads)
  bf16* w1s = (bf16*)(smem + 34816);   // 64 x 136
  bf16* w2s = (bf16*)(smem + 34816);   // 128 x 72 (same region, phase-alternated)
  int tid = threadIdx.x;
  int wave = tid>>6, l = tid&63, lo16 = l&15, quad = l>>4;
  int m0 = blockIdx.x*128;
  #pragma unroll
  for (int itn=0; itn<2; itn++){
    int px = (tid>>2) + itn*64;
    int q = tid&3;
    const float* xr = X2 + (size_t)(m0+px)*128 + q*32;
    float v[32];
    #pragma unroll
    for (int i=0;i<8;i++) *(float4*)(v+i*4) = *(const float4*)(xr+i*4);
    float s=0.f, ss=0.f;
    #pragma unroll
    for (int i=0;i<32;i++){ s += v[i]; ss += v[i]*v[i]; }
    s  += __shfl_xor(s,1,64);  ss += __shfl_xor(ss,1,64);
    s  += __shfl_xor(s,2,64);  ss += __shfl_xor(ss,2,64);
    float mean = s*(1.f/CC), var = ss*(1.f/CC)-mean*mean, rstd = rsqrtf(var+1e-5f);
    const float* gp = lng + q*32; const float* bp = lnb + q*32;
    uint4* dst = (uint4*)(&h0s[px*136 + q*32]);
    #pragma unroll
    for (int i=0;i<4;i++){
      float4 g0 = *(const float4*)(gp+i*8),  g1 = *(const float4*)(gp+i*8+4);
      float4 c0v = *(const float4*)(bp+i*8), c1v = *(const float4*)(bp+i*8+4);
      float o0 = (v[i*8+0]-mean)*rstd*g0.x + c0v.x;
      float o1 = (v[i*8+1]-mean)*rstd*g0.y + c0v.y;
      float o2 = (v[i*8+2]-mean)*rstd*g0.z + c0v.z;
      float o3 = (v[i*8+3]-mean)*rstd*g0.w + c0v.w;
      float o4 = (v[i*8+4]-mean)*rstd*g1.x + c1v.x;
      float o5 = (v[i*8+5]-mean)*rstd*g1.y + c1v.y;
      float o6 = (v[i*8+6]-mean)*rstd*g1.z + c1v.z;
      float o7 = (v[i*8+7]-mean)*rstd*g1.w + c1v.w;
      uint4 up; up.x = pk(o0,o1); up.y = pk(o2,o3); up.z = pk(o4,o5); up.w = pk(o6,o7);
      dst[i] = up;
    }
  }
  __syncthreads();
  short8 a1[2][4];
  #pragma unroll
  for (int mt=0;mt<2;mt++)
    #pragma unroll
    for (int ks=0;ks<4;ks++)
      a1[mt][ks] = *(const short8*)(&h0s[(wave*32 + mt*16 + lo16)*136 + ks*32 + quad*8]);
  f32x4 z = {0.f,0.f,0.f,0.f};
  f32x4 acc2[2][8];
  #pragma unroll
  for (int mt=0;mt<2;mt++)
    #pragma unroll
    for (int nt=0;nt<8;nt++) acc2[mt][nt]=z;

  for (int c0=0;c0<512;c0+=64){
    __syncthreads();
    #pragma unroll
    for (int it=0;it<4;it++){
      int e = it*2048 + tid*8;
      int nn = e>>7, kk = e&127;
      *(uint4*)(&w1s[nn*136 + kk]) = *(const uint4*)(w1t + (size_t)(c0+nn)*128 + kk);
    }
    __syncthreads();
    f32x4 acc1[2][4];
    #pragma unroll
    for (int mt=0;mt<2;mt++)
      #pragma unroll
      for (int nt=0;nt<4;nt++) acc1[mt][nt]=z;
    #pragma unroll
    for (int ks=0;ks<4;ks++)
      #pragma unroll
      for (int nt=0;nt<4;nt++){
        short8 bfr = *(const short8*)(&w1s[(nt*16+lo16)*136 + ks*32 + quad*8]);
        acc1[0][nt] = __builtin_amdgcn_mfma_f32_16x16x32_bf16(a1[0][ks], bfr, acc1[0][nt], 0,0,0);
        acc1[1][nt] = __builtin_amdgcn_mfma_f32_16x16x32_bf16(a1[1][ks], bfr, acc1[1][nt], 0,0,0);
      }
    #pragma unroll
    for (int mt=0;mt<2;mt++)
      #pragma unroll
      for (int nt=0;nt<4;nt++){
        float bb = b1[c0 + nt*16 + lo16];
        #pragma unroll
        for (int r=0;r<4;r++)
          ts[(wave*32 + mt*16 + quad*4 + r)*72 + nt*16 + lo16] = f2b(gelu_f(acc1[mt][nt][r] + bb));
      }
    __syncthreads();
    #pragma unroll
    for (int it=0;it<4;it++){
      int e = it*2048 + tid*8;
      int nn = e>>6, kk = e&63;
      *(uint4*)(&w2s[nn*72 + kk]) = *(const uint4*)(w2t + (size_t)nn*512 + c0 + kk);
    }
    __syncthreads();
    #pragma unroll
    for (int ks2=0;ks2<2;ks2++){
      short8 a2[2];
      #pragma unroll
      for (int mt=0;mt<2;mt++)
        a2[mt] = *(const short8*)(&ts[(wave*32 + mt*16 + lo16)*72 + ks2*32 + quad*8]);
      #pragma unroll
      for (int nt2=0;nt2<8;nt2++){
        short8 bfr2 = *(const short8*)(&w2s[(nt2*16+lo16)*72 + ks2*32 + quad*8]);
        acc2[0][nt2] = __builtin_amdgcn_mfma_f32_16x16x32_bf16(a2[0], bfr2, acc2[0][nt2], 0,0,0);
        acc2[1][nt2] = __builtin_amdgcn_mfma_f32_16x16x32_bf16(a2[1], bfr2, acc2[1][nt2], 0,0,0);
      }
    }
  }
  #pragma unroll
  for (int mt=0;mt<2;mt++)
    #pragma unroll
    for (int nt=0;nt<8;nt++){
      int col = nt*16 + lo16;
      float bb = b2[col];
      #pragma unroll
      for (int r=0;r<4;r++){
        int row = m0 + wave*32 + mt*16 + quad*4 + r;
        float v = acc2[mt][nt][r] + bb + X2[(size_t)row*128 + col];
        OUT[(size_t)row*128 + col] = v;
      }
    }
}

extern "C" void kernel_launch(void* const* d_in, const int* in_sizes, int n_in,
                              void* d_out, int out_size, void* d_ws, size_t ws_size,
                              hipStream_t stream)
{
  const float* x    = (const float*)d_in[0];
  const float* ln1g = (const float*)d_in[1];
  const float* ln1b = (const float*)d_in[2];
  const float* inw  = (const float*)d_in[3];
  const float* inb  = (const float*)d_in[4];
  const float* dwk  = (const float*)d_in[5];
  const float* dwb  = (const float*)d_in[6];
  const float* dwlng= (const float*)d_in[7];
  const float* dwlnb= (const float*)d_in[8];
  const float* offw = (const float*)d_in[9];
  const float* offb = (const float*)d_in[10];
  const float* maskw= (const float*)d_in[11];
  const float* maskb= (const float*)d_in[12];
  const float* outw = (const float*)d_in[13];
  const float* outb = (const float*)d_in[14];
  const float* ln2g = (const float*)d_in[15];
  const float* ln2b = (const float*)d_in[16];
  const float* fc1w = (const float*)d_in[17];
  const float* fc1b = (const float*)d_in[18];
  const float* fc2w = (const float*)d_in[19];
  const float* fc2b = (const float*)d_in[20];
  float* out = (float*)d_out;

  bf16* ws = (bf16*)d_ws;
  const size_t S = (size_t)NHW*CC;
  bf16* xn = ws;
  bf16* xp = ws + S;
  bf16* x1 = ws + 2*S;
  bf16* y  = xn;
  float* x2 = out;
  bf16* inwt  = ws + 3*S;
  bf16* outwt = inwt + 128*128;
  bf16* w1t   = outwt + 128*128;
  bf16* w2t   = w1t + 512*128;
  bf16* wsw   = w2t + 128*512;
  float* cw   = (float*)(wsw + 224*128);

  prep_k<<<753, 256, 0, stream>>>(inw, outw, fc1w, fc2w, offw, offb, maskw, maskb,
                                  inwt, outwt, w1t, w2t, wsw, cw);
  ln_k<<<NHW/4, 256, 0, stream>>>(x, ln1g, ln1b, xn);
  gemm_mfma<bf16,false><<<dim3(2,256), 256, 0, stream>>>(xn, inwt, inb, nullptr, xp);
  convln_k<<<NHW/16, 256, 0, stream>>>(xn, dwk, dwb, dwlng, dwlnb, x1);
  samp_k<<<NHW/32, 256, 0, stream>>>(x1, xp, wsw, cw, y);
  gemm_mfma<float,true><<<dim3(2,256), 256, 0, stream>>>(y, outwt, outb, x, x2);
  mlp_mfma<<<NHW/128, 256, 0, stream>>>(x2, ln2g, ln2b, w1t, fc1b, w2t, fc2b, out);
}